// Round 1
// baseline (260.337 us; speedup 1.0000x reference)
//
#include <hip/hip_runtime.h>

// GroupedEmbedding: out[r, :] = weights[r / IDS, values[r], :]
// T=8 tables, E=100000 embeddings, D=128, N=200000 ids/table.
constexpr int NUM_TABLES = 8;
constexpr int NUM_EMB    = 100000;
constexpr int DIM        = 128;
constexpr int IDS        = 200000;
constexpr int ROWS       = NUM_TABLES * IDS;   // 1,600,000

// 32 lanes handle one row (32 x float4 = 512 B), 8 rows per 256-thread block.
__global__ __launch_bounds__(256) void grouped_embedding_gather(
    const int* __restrict__ vals,
    const float* __restrict__ weights,
    float* __restrict__ out) {
  const int lane       = threadIdx.x & 31;   // float4 slot within the row
  const int rowInBlock = threadIdx.x >> 5;   // 0..7
  const int rowsPerBlk = blockDim.x >> 5;    // 8
  const int rowStride  = gridDim.x * rowsPerBlk;

  for (int r = blockIdx.x * rowsPerBlk + rowInBlock; r < ROWS; r += rowStride) {
    const int id = vals[r];            // broadcast across the 32-lane group
    const int t  = r / IDS;            // table index (magic-mul division)
    const float4* __restrict__ src = reinterpret_cast<const float4*>(
        weights + ((size_t)t * NUM_EMB + (size_t)id) * DIM);
    float4* __restrict__ dst = reinterpret_cast<float4*>(
        out + (size_t)r * DIM);
    dst[lane] = src[lane];
  }
}

extern "C" void kernel_launch(void* const* d_in, const int* in_sizes, int n_in,
                              void* d_out, int out_size, void* d_ws, size_t ws_size,
                              hipStream_t stream) {
  const int*   vals    = (const int*)d_in[0];
  const float* weights = (const float*)d_in[1];
  float*       out     = (float*)d_out;

  // 2048 blocks x 4 waves = 8192 waves = 32 waves/CU on 256 CUs (full occupancy).
  const int blocks = 2048;
  grouped_embedding_gather<<<blocks, 256, 0, stream>>>(vals, weights, out);
}

// Round 3
// 256.706 us; speedup vs baseline: 1.0141x; 1.0141x over previous
//
#include <hip/hip_runtime.h>

// GroupedEmbedding: out[r, :] = weights[r / IDS, values[r], :]
// T=8 tables, E=100000 embeddings, D=128, N=200000 ids/table.
constexpr int NUM_TABLES = 8;
constexpr int NUM_EMB    = 100000;
constexpr int DIM        = 128;
constexpr int IDS        = 200000;
constexpr int ROWS       = NUM_TABLES * IDS;   // 1,600,000

// Native vector type: __builtin_nontemporal_store rejects HIP's float4 class.
typedef float floatx4 __attribute__((ext_vector_type(4)));

// 32 lanes handle one row (32 x 16B = 512 B), 8 rows per 256-thread block.
// Stores are non-temporal so the 819 MB output stream does not evict the
// weight rows (51.2 MB live table window, 2x average reuse) from L2/L3.
__global__ __launch_bounds__(256) void grouped_embedding_gather(
    const int* __restrict__ vals,
    const float* __restrict__ weights,
    float* __restrict__ out) {
  const int lane       = threadIdx.x & 31;   // 16B slot within the row
  const int rowInBlock = threadIdx.x >> 5;   // 0..7
  const int rowsPerBlk = blockDim.x >> 5;    // 8
  const int rowStride  = gridDim.x * rowsPerBlk;

  for (int r = blockIdx.x * rowsPerBlk + rowInBlock; r < ROWS; r += rowStride) {
    const int id = __builtin_nontemporal_load(vals + r);  // streamed once
    const int t  = r / IDS;            // table index (magic-mul division)
    const floatx4* __restrict__ src = reinterpret_cast<const floatx4*>(
        weights + ((size_t)t * NUM_EMB + (size_t)id) * DIM);
    floatx4 v = src[lane];             // cached: 2x reuse within the table
    floatx4* dst = reinterpret_cast<floatx4*>(out + (size_t)r * DIM) + lane;
    __builtin_nontemporal_store(v, dst);
  }
}

extern "C" void kernel_launch(void* const* d_in, const int* in_sizes, int n_in,
                              void* d_out, int out_size, void* d_ws, size_t ws_size,
                              hipStream_t stream) {
  const int*   vals    = (const int*)d_in[0];
  const float* weights = (const float*)d_in[1];
  float*       out     = (float*)d_out;

  // 2048 blocks x 4 waves = 8192 waves = 32 waves/CU on 256 CUs (full occupancy).
  const int blocks = 2048;
  grouped_embedding_gather<<<blocks, 256, 0, stream>>>(vals, weights, out);
}